// Round 20
// baseline (173.562 us; speedup 1.0000x reference)
//
#include <hip/hip_runtime.h>
#include <hip/hip_bf16.h>

typedef short bf16x8 __attribute__((ext_vector_type(8)));
typedef float f32x4 __attribute__((ext_vector_type(4)));
typedef unsigned short u16x4 __attribute__((ext_vector_type(4)));

static constexpr int M_DIM = 16384;
static constexpr int N_DIM = 4096;
static constexpr int K_DIM = 1024;

static constexpr int WT_BLOCKS  = 128;                         // one per j, FIRST
static constexpr int CVT_BLOCKS = (M_DIM * K_DIM / 4) / 1024;  // 4096 (16 f32/thread)

__device__ __forceinline__ unsigned short f2bf(float f) {
  union { float f; unsigned u; } v; v.f = f;
  unsigned r = v.u + 0x7FFFu + ((v.u >> 16) & 1u);
  return (unsigned short)(r >> 16);
}

// Fused prep; R20: NT loads on x (read-once) + NT stores on xb/wT (write-once,
// re-read only by the NEXT dispatch; 40MB > L2 so they'd be evicted anyway).
__global__ __launch_bounds__(256) void prep_kernel(
    const float* __restrict__ x, const float* __restrict__ a,
    const float* __restrict__ b, const float* __restrict__ s,
    unsigned short* __restrict__ xb, unsigned short* __restrict__ wT) {
  const int tid = threadIdx.x;

  if (blockIdx.x >= WT_BLOCKS) {
    const int base = (blockIdx.x - WT_BLOCKS) * 1024;   // float4 units
    const f32x4* xf = reinterpret_cast<const f32x4*>(x);
    u16x4* xo = reinterpret_cast<u16x4*>(xb);
#pragma unroll
    for (int q = 0; q < 4; ++q) {
      f32x4 v = __builtin_nontemporal_load(&xf[base + q * 256 + tid]);
      u16x4 o;
      o[0] = f2bf(v[0]); o[1] = f2bf(v[1]); o[2] = f2bf(v[2]); o[3] = f2bf(v[3]);
      __builtin_nontemporal_store(o, &xo[base + q * 256 + tid]);
    }
    return;
  }

  __shared__ float as_eff[512];       // [r*64+i]
  __shared__ float bsh[32 * 132];     // [l][rk], pad 132
  const int j = blockIdx.x;

#pragma unroll
  for (int t = tid; t < 512; t += 256)
    as_eff[t] = a[(size_t)t * 128 + j] * s[(t & 63) * 128 + j];
#pragma unroll
  for (int t = tid; t < 4096; t += 256)
    bsh[(t & 31) * 132 + (t >> 5)] = b[t];     // b[rk*32+l] -> [l][rk]
  __syncthreads();

  const int i = tid >> 2;
  const int kk0 = (tid & 3) * 4;
  float av[8];
#pragma unroll
  for (int r = 0; r < 8; ++r) av[r] = as_eff[r * 64 + i];

#pragma unroll 4
  for (int l = 0; l < 32; ++l) {
    float o[4] = {0.f, 0.f, 0.f, 0.f};
#pragma unroll
    for (int r = 0; r < 8; ++r) {
      float4 bv4 = *reinterpret_cast<const float4*>(&bsh[l * 132 + r * 16 + kk0]);
      o[0] += av[r] * bv4.x; o[1] += av[r] * bv4.y;
      o[2] += av[r] * bv4.z; o[3] += av[r] * bv4.w;
    }
    u16x4 w4;
    w4[0] = f2bf(o[0]); w4[1] = f2bf(o[1]); w4[2] = f2bf(o[2]); w4[3] = f2bf(o[3]);
    __builtin_nontemporal_store(w4,
        reinterpret_cast<u16x4*>(&wT[(size_t)(j * 32 + l) * K_DIM + tid * 4]));
  }
}

// ---- R19-proven 256x256 GEMM with NT C-stores — byte-identical ----
#define PH_BARRIER __builtin_amdgcn_s_barrier()
#define SCHED0     __builtin_amdgcn_sched_barrier(0)
#define WAITV(N)   do { asm volatile("s_waitcnt vmcnt(" #N ")" ::: "memory"); SCHED0; } while (0)
#define WAITL(N)   do { asm volatile("s_waitcnt lgkmcnt(" #N ")" ::: "memory"); SCHED0; } while (0)

__device__ __forceinline__ void quad_mfma(f32x4 (&acc)[8][4], const bf16x8 (&aH)[4][2],
                                          const bf16x8 (&bH)[2][2], int mbase, int nbase) {
  __builtin_amdgcn_s_setprio(1);
#pragma unroll
  for (int ks = 0; ks < 2; ++ks)
#pragma unroll
    for (int mi = 0; mi < 4; ++mi)
#pragma unroll
      for (int ni = 0; ni < 2; ++ni)
        acc[mbase + mi][nbase + ni] = __builtin_amdgcn_mfma_f32_16x16x32_bf16(
            aH[mi][ks], bH[ni][ks], acc[mbase + mi][nbase + ni], 0, 0, 0);
  __builtin_amdgcn_s_setprio(0);
}

__global__ __launch_bounds__(512, 2) void gemm8_kernel(
    const unsigned short* __restrict__ A, const unsigned short* __restrict__ BT,
    const float* __restrict__ bias, float* __restrict__ C) {
  __shared__ __align__(16) unsigned short Al[2][16384];
  __shared__ __align__(16) unsigned short Bl[2][16384];

  const int tid  = threadIdx.x;
  const int lane = tid & 63;
  const int wave = tid >> 6;
  const int wm = wave >> 2;
  const int wn = wave & 3;
  const int wr = wm * 128;
  const int wc = wn * 64;
  const int frow = lane & 15;
  const int kg = lane >> 4;
  const int swz0 = (kg * 16) ^ ((lane & 7) << 4);
  const int swz1 = (64 + kg * 16) ^ ((lane & 7) << 4);

  int bid = blockIdx.x;
  int gid = bid >> 4, lid = bid & 15;
  gid = ((gid & 7) << 3) | (gid >> 3);
  const int bm = (gid >> 2) * 4 + (lid >> 2);
  const int bn = (gid & 3) * 4 + (lid & 3);
  const int brow = bm * 256, bcol = bn * 256;

  const unsigned short* Abase = A + (size_t)brow * K_DIM;
  const unsigned short* Bbase = BT + (size_t)bcol * K_DIM;

  const int srow = tid >> 3;
  const int scol = ((((tid & 7) << 4) ^ ((srow & 7) << 4)) >> 1);
  const int ldsu = __builtin_amdgcn_readfirstlane(wave * 512);

#define STG(dst, base, q, k0) __builtin_amdgcn_global_load_lds( \
    (const __attribute__((address_space(1))) void*)((base) + (size_t)((q)*64 + srow) * K_DIM + (k0) + scol), \
    (__attribute__((address_space(3))) void*)((dst) + (q)*4096 + ldsu), 16, 0, 0)

#define STG4(dst, base, k0) do { STG(dst, base, 0, k0); STG(dst, base, 1, k0); \
                                 STG(dst, base, 2, k0); STG(dst, base, 3, k0); } while (0)

#define LOAD_AH(P, h, dst) { _Pragma("unroll") for (int mi = 0; mi < 4; ++mi) { \
    const char* p_ = (const char*)(P) + (wr + frow + ((h)*4 + mi) * 16) * 128; \
    dst[mi][0] = *(const bf16x8*)(p_ + swz0); dst[mi][1] = *(const bf16x8*)(p_ + swz1); } }

#define LOAD_BH(P, h, dst) { _Pragma("unroll") for (int ni = 0; ni < 2; ++ni) { \
    const char* p_ = (const char*)(P) + (wc + frow + ((h)*2 + ni) * 16) * 128; \
    dst[ni][0] = *(const bf16x8*)(p_ + swz0); dst[ni][1] = *(const bf16x8*)(p_ + swz1); } }

  f32x4 acc[8][4] = {};
  bf16x8 aF0[4][2], aF1[4][2], b0[2][2], b1[2][2];

  STG4(Bl[0], Bbase, 0);
  STG4(Al[0], Abase, 0);
  STG4(Bl[1], Bbase, 64);
  WAITV(4);
  PH_BARRIER;

#define TILE(PA, PB, SA, SB, VM) \
  LOAD_AH(PA, 0, aF0); SCHED0; \
  LOAD_BH(PB, 0, b0);  SCHED0; \
  LOAD_BH(PB, 1, b1);  SCHED0; \
  LOAD_AH(PA, 1, aF1); SCHED0; \
  SA; \
  WAITL(12); \
  quad_mfma(acc, aF0, b0, 0, 0); \
  WAITL(8); \
  quad_mfma(acc, aF0, b1, 0, 2); \
  WAITL(0); \
  PH_BARRIER; \
  SB; \
  quad_mfma(acc, aF1, b0, 4, 0); \
  quad_mfma(acc, aF1, b1, 4, 2); \
  VM; \
  PH_BARRIER;

  int k = 0;
#pragma unroll 1
  for (int i = 0; i < 7; ++i) {
    TILE(Al[0], Bl[0], STG4(Al[1], Abase, k + 64), STG4(Bl[0], Bbase, k + 128), WAITV(4));
    TILE(Al[1], Bl[1], STG4(Al[0], Abase, k + 128), STG4(Bl[1], Bbase, k + 192), WAITV(4));
    k += 128;
  }
  TILE(Al[0], Bl[0], STG4(Al[1], Abase, k + 64), (void)0, WAITV(0));
  TILE(Al[1], Bl[1], (void)0, (void)0, WAITV(0));

  __syncthreads();
  float* T = (float*)&Al[0][0];
  float* Tw = T + wave * (16 * 68);
  const int col4 = lane & 15;
  const int rsel = lane >> 4;
  float4 bv = *(const float4*)&bias[bcol + wc + col4 * 4];

#pragma unroll
  for (int mi = 0; mi < 8; ++mi) {
#pragma unroll
    for (int ni = 0; ni < 4; ++ni)
#pragma unroll
      for (int r = 0; r < 4; ++r)
        Tw[(kg * 4 + r) * 68 + ni * 16 + frow] = acc[mi][ni][r];
    WAITL(0);
#pragma unroll
    for (int rr = 0; rr < 4; ++rr) {
      f32x4 v = *(f32x4*)&Tw[(rr * 4 + rsel) * 68 + col4 * 4];
      v[0] += bv.x; v[1] += bv.y; v[2] += bv.z; v[3] += bv.w;
      __builtin_nontemporal_store(v,
          (f32x4*)&C[(size_t)(brow + wr + mi * 16 + rr * 4 + rsel) * N_DIM + bcol + wc + col4 * 4]);
    }
    WAITL(0);
  }
}

extern "C" void kernel_launch(void* const* d_in, const int* in_sizes, int n_in,
                              void* d_out, int out_size, void* d_ws, size_t ws_size,
                              hipStream_t stream) {
  const float* x    = (const float*)d_in[0];
  const float* a    = (const float*)d_in[1];
  const float* b    = (const float*)d_in[2];
  const float* s    = (const float*)d_in[3];
  const float* bias = (const float*)d_in[4];
  float* out = (float*)d_out;

  unsigned short* xb = (unsigned short*)d_ws;                                        // 32 MB
  unsigned short* wT = (unsigned short*)((char*)d_ws + (size_t)M_DIM * K_DIM * 2);   // 8 MB

  prep_kernel<<<WT_BLOCKS + CVT_BLOCKS, 256, 0, stream>>>(x, a, b, s, xb, wT);
  gemm8_kernel<<<(M_DIM / 256) * (N_DIM / 256), 512, 0, stream>>>(xb, wT, bias, out);
}

// Round 21
// 162.683 us; speedup vs baseline: 1.0669x; 1.0669x over previous
//
#include <hip/hip_runtime.h>
#include <hip/hip_bf16.h>

typedef short bf16x8 __attribute__((ext_vector_type(8)));
typedef float f32x4 __attribute__((ext_vector_type(4)));
typedef unsigned short u16x4 __attribute__((ext_vector_type(4)));

static constexpr int M_DIM = 16384;
static constexpr int N_DIM = 4096;
static constexpr int K_DIM = 1024;

static constexpr int WT_BLOCKS  = 128;                         // one per j, FIRST
static constexpr int CVT_BLOCKS = (M_DIM * K_DIM / 4) / 1024;  // 4096 (16 f32/thread)

__device__ __forceinline__ unsigned short f2bf(float f) {
  union { float f; unsigned u; } v; v.f = f;
  unsigned r = v.u + 0x7FFFu + ((v.u >> 16) & 1u);
  return (unsigned short)(r >> 16);
}

// Fused prep. R21: NT LOADS on x only (read-once, no-allocate is safe).
// xb/wT stores are CACHED (R20 lesson: NT stores bypassed L3; the gemm's
// 147MB input fetch was L3-served in R19 — wT 8MB resident, xb hot — and
// went to raw HBM in R20, costing the gemm ~20us. Producer->consumer
// intermediates must stay cacheable; NT only for never-re-read data like C).
__global__ __launch_bounds__(256) void prep_kernel(
    const float* __restrict__ x, const float* __restrict__ a,
    const float* __restrict__ b, const float* __restrict__ s,
    unsigned short* __restrict__ xb, unsigned short* __restrict__ wT) {
  const int tid = threadIdx.x;

  if (blockIdx.x >= WT_BLOCKS) {
    const int base = (blockIdx.x - WT_BLOCKS) * 1024;   // float4 units
    const f32x4* xf = reinterpret_cast<const f32x4*>(x);
    u16x4* xo = reinterpret_cast<u16x4*>(xb);
#pragma unroll
    for (int q = 0; q < 4; ++q) {
      f32x4 v = __builtin_nontemporal_load(&xf[base + q * 256 + tid]);
      u16x4 o;
      o[0] = f2bf(v[0]); o[1] = f2bf(v[1]); o[2] = f2bf(v[2]); o[3] = f2bf(v[3]);
      xo[base + q * 256 + tid] = o;                     // cached store
    }
    return;
  }

  __shared__ float as_eff[512];       // [r*64+i]
  __shared__ float bsh[32 * 132];     // [l][rk], pad 132
  const int j = blockIdx.x;

#pragma unroll
  for (int t = tid; t < 512; t += 256)
    as_eff[t] = a[(size_t)t * 128 + j] * s[(t & 63) * 128 + j];
#pragma unroll
  for (int t = tid; t < 4096; t += 256)
    bsh[(t & 31) * 132 + (t >> 5)] = b[t];     // b[rk*32+l] -> [l][rk]
  __syncthreads();

  const int i = tid >> 2;
  const int kk0 = (tid & 3) * 4;
  float av[8];
#pragma unroll
  for (int r = 0; r < 8; ++r) av[r] = as_eff[r * 64 + i];

#pragma unroll 4
  for (int l = 0; l < 32; ++l) {
    float o[4] = {0.f, 0.f, 0.f, 0.f};
#pragma unroll
    for (int r = 0; r < 8; ++r) {
      float4 bv4 = *reinterpret_cast<const float4*>(&bsh[l * 132 + r * 16 + kk0]);
      o[0] += av[r] * bv4.x; o[1] += av[r] * bv4.y;
      o[2] += av[r] * bv4.z; o[3] += av[r] * bv4.w;
    }
    ushort4 w4;
    w4.x = f2bf(o[0]); w4.y = f2bf(o[1]); w4.z = f2bf(o[2]); w4.w = f2bf(o[3]);
    *reinterpret_cast<ushort4*>(&wT[(size_t)(j * 32 + l) * K_DIM + tid * 4]) = w4;  // cached
  }
}

// ---- R19-proven 256x256 GEMM with NT C-stores — byte-identical ----
#define PH_BARRIER __builtin_amdgcn_s_barrier()
#define SCHED0     __builtin_amdgcn_sched_barrier(0)
#define WAITV(N)   do { asm volatile("s_waitcnt vmcnt(" #N ")" ::: "memory"); SCHED0; } while (0)
#define WAITL(N)   do { asm volatile("s_waitcnt lgkmcnt(" #N ")" ::: "memory"); SCHED0; } while (0)

__device__ __forceinline__ void quad_mfma(f32x4 (&acc)[8][4], const bf16x8 (&aH)[4][2],
                                          const bf16x8 (&bH)[2][2], int mbase, int nbase) {
  __builtin_amdgcn_s_setprio(1);
#pragma unroll
  for (int ks = 0; ks < 2; ++ks)
#pragma unroll
    for (int mi = 0; mi < 4; ++mi)
#pragma unroll
      for (int ni = 0; ni < 2; ++ni)
        acc[mbase + mi][nbase + ni] = __builtin_amdgcn_mfma_f32_16x16x32_bf16(
            aH[mi][ks], bH[ni][ks], acc[mbase + mi][nbase + ni], 0, 0, 0);
  __builtin_amdgcn_s_setprio(0);
}

__global__ __launch_bounds__(512, 2) void gemm8_kernel(
    const unsigned short* __restrict__ A, const unsigned short* __restrict__ BT,
    const float* __restrict__ bias, float* __restrict__ C) {
  __shared__ __align__(16) unsigned short Al[2][16384];
  __shared__ __align__(16) unsigned short Bl[2][16384];

  const int tid  = threadIdx.x;
  const int lane = tid & 63;
  const int wave = tid >> 6;
  const int wm = wave >> 2;
  const int wn = wave & 3;
  const int wr = wm * 128;
  const int wc = wn * 64;
  const int frow = lane & 15;
  const int kg = lane >> 4;
  const int swz0 = (kg * 16) ^ ((lane & 7) << 4);
  const int swz1 = (64 + kg * 16) ^ ((lane & 7) << 4);

  int bid = blockIdx.x;
  int gid = bid >> 4, lid = bid & 15;
  gid = ((gid & 7) << 3) | (gid >> 3);
  const int bm = (gid >> 2) * 4 + (lid >> 2);
  const int bn = (gid & 3) * 4 + (lid & 3);
  const int brow = bm * 256, bcol = bn * 256;

  const unsigned short* Abase = A + (size_t)brow * K_DIM;
  const unsigned short* Bbase = BT + (size_t)bcol * K_DIM;

  const int srow = tid >> 3;
  const int scol = ((((tid & 7) << 4) ^ ((srow & 7) << 4)) >> 1);
  const int ldsu = __builtin_amdgcn_readfirstlane(wave * 512);

#define STG(dst, base, q, k0) __builtin_amdgcn_global_load_lds( \
    (const __attribute__((address_space(1))) void*)((base) + (size_t)((q)*64 + srow) * K_DIM + (k0) + scol), \
    (__attribute__((address_space(3))) void*)((dst) + (q)*4096 + ldsu), 16, 0, 0)

#define STG4(dst, base, k0) do { STG(dst, base, 0, k0); STG(dst, base, 1, k0); \
                                 STG(dst, base, 2, k0); STG(dst, base, 3, k0); } while (0)

#define LOAD_AH(P, h, dst) { _Pragma("unroll") for (int mi = 0; mi < 4; ++mi) { \
    const char* p_ = (const char*)(P) + (wr + frow + ((h)*4 + mi) * 16) * 128; \
    dst[mi][0] = *(const bf16x8*)(p_ + swz0); dst[mi][1] = *(const bf16x8*)(p_ + swz1); } }

#define LOAD_BH(P, h, dst) { _Pragma("unroll") for (int ni = 0; ni < 2; ++ni) { \
    const char* p_ = (const char*)(P) + (wc + frow + ((h)*2 + ni) * 16) * 128; \
    dst[ni][0] = *(const bf16x8*)(p_ + swz0); dst[ni][1] = *(const bf16x8*)(p_ + swz1); } }

  f32x4 acc[8][4] = {};
  bf16x8 aF0[4][2], aF1[4][2], b0[2][2], b1[2][2];

  STG4(Bl[0], Bbase, 0);
  STG4(Al[0], Abase, 0);
  STG4(Bl[1], Bbase, 64);
  WAITV(4);
  PH_BARRIER;

#define TILE(PA, PB, SA, SB, VM) \
  LOAD_AH(PA, 0, aF0); SCHED0; \
  LOAD_BH(PB, 0, b0);  SCHED0; \
  LOAD_BH(PB, 1, b1);  SCHED0; \
  LOAD_AH(PA, 1, aF1); SCHED0; \
  SA; \
  WAITL(12); \
  quad_mfma(acc, aF0, b0, 0, 0); \
  WAITL(8); \
  quad_mfma(acc, aF0, b1, 0, 2); \
  WAITL(0); \
  PH_BARRIER; \
  SB; \
  quad_mfma(acc, aF1, b0, 4, 0); \
  quad_mfma(acc, aF1, b1, 4, 2); \
  VM; \
  PH_BARRIER;

  int k = 0;
#pragma unroll 1
  for (int i = 0; i < 7; ++i) {
    TILE(Al[0], Bl[0], STG4(Al[1], Abase, k + 64), STG4(Bl[0], Bbase, k + 128), WAITV(4));
    TILE(Al[1], Bl[1], STG4(Al[0], Abase, k + 128), STG4(Bl[1], Bbase, k + 192), WAITV(4));
    k += 128;
  }
  TILE(Al[0], Bl[0], STG4(Al[1], Abase, k + 64), (void)0, WAITV(0));
  TILE(Al[1], Bl[1], (void)0, (void)0, WAITV(0));

  __syncthreads();
  float* T = (float*)&Al[0][0];
  float* Tw = T + wave * (16 * 68);
  const int col4 = lane & 15;
  const int rsel = lane >> 4;
  float4 bv = *(const float4*)&bias[bcol + wc + col4 * 4];

#pragma unroll
  for (int mi = 0; mi < 8; ++mi) {
#pragma unroll
    for (int ni = 0; ni < 4; ++ni)
#pragma unroll
      for (int r = 0; r < 4; ++r)
        Tw[(kg * 4 + r) * 68 + ni * 16 + frow] = acc[mi][ni][r];
    WAITL(0);
#pragma unroll
    for (int rr = 0; rr < 4; ++rr) {
      f32x4 v = *(f32x4*)&Tw[(rr * 4 + rsel) * 68 + col4 * 4];
      v[0] += bv.x; v[1] += bv.y; v[2] += bv.z; v[3] += bv.w;
      __builtin_nontemporal_store(v,
          (f32x4*)&C[(size_t)(brow + wr + mi * 16 + rr * 4 + rsel) * N_DIM + bcol + wc + col4 * 4]);
    }
    WAITL(0);
  }
}

extern "C" void kernel_launch(void* const* d_in, const int* in_sizes, int n_in,
                              void* d_out, int out_size, void* d_ws, size_t ws_size,
                              hipStream_t stream) {
  const float* x    = (const float*)d_in[0];
  const float* a    = (const float*)d_in[1];
  const float* b    = (const float*)d_in[2];
  const float* s    = (const float*)d_in[3];
  const float* bias = (const float*)d_in[4];
  float* out = (float*)d_out;

  unsigned short* xb = (unsigned short*)d_ws;                                        // 32 MB
  unsigned short* wT = (unsigned short*)((char*)d_ws + (size_t)M_DIM * K_DIM * 2);   // 8 MB

  prep_kernel<<<WT_BLOCKS + CVT_BLOCKS, 256, 0, stream>>>(x, a, b, s, xb, wT);
  gemm8_kernel<<<(M_DIM / 256) * (N_DIM / 256), 512, 0, stream>>>(xb, wT, bias, out);
}

// Round 22
// 160.769 us; speedup vs baseline: 1.0796x; 1.0119x over previous
//
#include <hip/hip_runtime.h>
#include <hip/hip_bf16.h>

typedef short bf16x8 __attribute__((ext_vector_type(8)));
typedef float f32x4 __attribute__((ext_vector_type(4)));

static constexpr int M_DIM = 16384;
static constexpr int N_DIM = 4096;
static constexpr int K_DIM = 1024;

static constexpr int WT_BLOCKS  = 128;                         // one per j, FIRST
static constexpr int CVT_BLOCKS = (M_DIM * K_DIM / 4) / 1024;  // 4096 (16 f32/thread)

__device__ __forceinline__ unsigned short f2bf(float f) {
  union { float f; unsigned u; } v; v.f = f;
  unsigned r = v.u + 0x7FFFu + ((v.u >> 16) & 1u);
  return (unsigned short)(r >> 16);
}

// R19-proven fused prep (cached loads+stores; intermediates must stay cacheable
// — R20 showed NT stores on xb/wT cost the gemm ~20us by bypassing L3).
__global__ __launch_bounds__(256) void prep_kernel(
    const float* __restrict__ x, const float* __restrict__ a,
    const float* __restrict__ b, const float* __restrict__ s,
    unsigned short* __restrict__ xb, unsigned short* __restrict__ wT) {
  const int tid = threadIdx.x;

  if (blockIdx.x >= WT_BLOCKS) {
    const int base = (blockIdx.x - WT_BLOCKS) * 1024;   // float4 units
    const float4* xf = reinterpret_cast<const float4*>(x);
    ushort4* xo = reinterpret_cast<ushort4*>(xb);
#pragma unroll
    for (int q = 0; q < 4; ++q) {
      float4 v = xf[base + q * 256 + tid];
      ushort4 o;
      o.x = f2bf(v.x); o.y = f2bf(v.y); o.z = f2bf(v.z); o.w = f2bf(v.w);
      xo[base + q * 256 + tid] = o;
    }
    return;
  }

  __shared__ float as_eff[512];       // [r*64+i]
  __shared__ float bsh[32 * 132];     // [l][rk], pad 132
  const int j = blockIdx.x;

#pragma unroll
  for (int t = tid; t < 512; t += 256)
    as_eff[t] = a[(size_t)t * 128 + j] * s[(t & 63) * 128 + j];
#pragma unroll
  for (int t = tid; t < 4096; t += 256)
    bsh[(t & 31) * 132 + (t >> 5)] = b[t];     // b[rk*32+l] -> [l][rk]
  __syncthreads();

  const int i = tid >> 2;
  const int kk0 = (tid & 3) * 4;
  float av[8];
#pragma unroll
  for (int r = 0; r < 8; ++r) av[r] = as_eff[r * 64 + i];

#pragma unroll 4
  for (int l = 0; l < 32; ++l) {
    float o[4] = {0.f, 0.f, 0.f, 0.f};
#pragma unroll
    for (int r = 0; r < 8; ++r) {
      float4 bv4 = *reinterpret_cast<const float4*>(&bsh[l * 132 + r * 16 + kk0]);
      o[0] += av[r] * bv4.x; o[1] += av[r] * bv4.y;
      o[2] += av[r] * bv4.z; o[3] += av[r] * bv4.w;
    }
    ushort4 w4;
    w4.x = f2bf(o[0]); w4.y = f2bf(o[1]); w4.z = f2bf(o[2]); w4.w = f2bf(o[3]);
    *reinterpret_cast<ushort4*>(&wT[(size_t)(j * 32 + l) * K_DIM + tid * 4]) = w4;
  }
}

// ---- R19-proven 256x256 GEMM (16x16x32, 2-barrier counted-wait K-loop,
// XOR-swizzled LDS, NT C-stores) — byte-identical to the 160.9us best ----
#define PH_BARRIER __builtin_amdgcn_s_barrier()
#define SCHED0     __builtin_amdgcn_sched_barrier(0)
#define WAITV(N)   do { asm volatile("s_waitcnt vmcnt(" #N ")" ::: "memory"); SCHED0; } while (0)
#define WAITL(N)   do { asm volatile("s_waitcnt lgkmcnt(" #N ")" ::: "memory"); SCHED0; } while (0)

__device__ __forceinline__ void quad_mfma(f32x4 (&acc)[8][4], const bf16x8 (&aH)[4][2],
                                          const bf16x8 (&bH)[2][2], int mbase, int nbase) {
  __builtin_amdgcn_s_setprio(1);
#pragma unroll
  for (int ks = 0; ks < 2; ++ks)
#pragma unroll
    for (int mi = 0; mi < 4; ++mi)
#pragma unroll
      for (int ni = 0; ni < 2; ++ni)
        acc[mbase + mi][nbase + ni] = __builtin_amdgcn_mfma_f32_16x16x32_bf16(
            aH[mi][ks], bH[ni][ks], acc[mbase + mi][nbase + ni], 0, 0, 0);
  __builtin_amdgcn_s_setprio(0);
}

__global__ __launch_bounds__(512, 2) void gemm8_kernel(
    const unsigned short* __restrict__ A, const unsigned short* __restrict__ BT,
    const float* __restrict__ bias, float* __restrict__ C) {
  __shared__ __align__(16) unsigned short Al[2][16384];
  __shared__ __align__(16) unsigned short Bl[2][16384];

  const int tid  = threadIdx.x;
  const int lane = tid & 63;
  const int wave = tid >> 6;
  const int wm = wave >> 2;
  const int wn = wave & 3;
  const int wr = wm * 128;
  const int wc = wn * 64;
  const int frow = lane & 15;
  const int kg = lane >> 4;
  const int swz0 = (kg * 16) ^ ((lane & 7) << 4);
  const int swz1 = (64 + kg * 16) ^ ((lane & 7) << 4);

  int bid = blockIdx.x;
  int gid = bid >> 4, lid = bid & 15;
  gid = ((gid & 7) << 3) | (gid >> 3);
  const int bm = (gid >> 2) * 4 + (lid >> 2);
  const int bn = (gid & 3) * 4 + (lid & 3);
  const int brow = bm * 256, bcol = bn * 256;

  const unsigned short* Abase = A + (size_t)brow * K_DIM;
  const unsigned short* Bbase = BT + (size_t)bcol * K_DIM;

  const int srow = tid >> 3;
  const int scol = ((((tid & 7) << 4) ^ ((srow & 7) << 4)) >> 1);
  const int ldsu = __builtin_amdgcn_readfirstlane(wave * 512);

#define STG(dst, base, q, k0) __builtin_amdgcn_global_load_lds( \
    (const __attribute__((address_space(1))) void*)((base) + (size_t)((q)*64 + srow) * K_DIM + (k0) + scol), \
    (__attribute__((address_space(3))) void*)((dst) + (q)*4096 + ldsu), 16, 0, 0)

#define STG4(dst, base, k0) do { STG(dst, base, 0, k0); STG(dst, base, 1, k0); \
                                 STG(dst, base, 2, k0); STG(dst, base, 3, k0); } while (0)

#define LOAD_AH(P, h, dst) { _Pragma("unroll") for (int mi = 0; mi < 4; ++mi) { \
    const char* p_ = (const char*)(P) + (wr + frow + ((h)*4 + mi) * 16) * 128; \
    dst[mi][0] = *(const bf16x8*)(p_ + swz0); dst[mi][1] = *(const bf16x8*)(p_ + swz1); } }

#define LOAD_BH(P, h, dst) { _Pragma("unroll") for (int ni = 0; ni < 2; ++ni) { \
    const char* p_ = (const char*)(P) + (wc + frow + ((h)*2 + ni) * 16) * 128; \
    dst[ni][0] = *(const bf16x8*)(p_ + swz0); dst[ni][1] = *(const bf16x8*)(p_ + swz1); } }

  f32x4 acc[8][4] = {};
  bf16x8 aF0[4][2], aF1[4][2], b0[2][2], b1[2][2];

  STG4(Bl[0], Bbase, 0);
  STG4(Al[0], Abase, 0);
  STG4(Bl[1], Bbase, 64);
  WAITV(4);
  PH_BARRIER;

#define TILE(PA, PB, SA, SB, VM) \
  LOAD_AH(PA, 0, aF0); SCHED0; \
  LOAD_BH(PB, 0, b0);  SCHED0; \
  LOAD_BH(PB, 1, b1);  SCHED0; \
  LOAD_AH(PA, 1, aF1); SCHED0; \
  SA; \
  WAITL(12); \
  quad_mfma(acc, aF0, b0, 0, 0); \
  WAITL(8); \
  quad_mfma(acc, aF0, b1, 0, 2); \
  WAITL(0); \
  PH_BARRIER; \
  SB; \
  quad_mfma(acc, aF1, b0, 4, 0); \
  quad_mfma(acc, aF1, b1, 4, 2); \
  VM; \
  PH_BARRIER;

  int k = 0;
#pragma unroll 1
  for (int i = 0; i < 7; ++i) {
    TILE(Al[0], Bl[0], STG4(Al[1], Abase, k + 64), STG4(Bl[0], Bbase, k + 128), WAITV(4));
    TILE(Al[1], Bl[1], STG4(Al[0], Abase, k + 128), STG4(Bl[1], Bbase, k + 192), WAITV(4));
    k += 128;
  }
  TILE(Al[0], Bl[0], STG4(Al[1], Abase, k + 64), (void)0, WAITV(0));
  TILE(Al[1], Bl[1], (void)0, (void)0, WAITV(0));

  __syncthreads();
  float* T = (float*)&Al[0][0];
  float* Tw = T + wave * (16 * 68);
  const int col4 = lane & 15;
  const int rsel = lane >> 4;
  float4 bv = *(const float4*)&bias[bcol + wc + col4 * 4];

#pragma unroll
  for (int mi = 0; mi < 8; ++mi) {
#pragma unroll
    for (int ni = 0; ni < 4; ++ni)
#pragma unroll
      for (int r = 0; r < 4; ++r)
        Tw[(kg * 4 + r) * 68 + ni * 16 + frow] = acc[mi][ni][r];
    WAITL(0);
#pragma unroll
    for (int rr = 0; rr < 4; ++rr) {
      f32x4 v = *(f32x4*)&Tw[(rr * 4 + rsel) * 68 + col4 * 4];
      v[0] += bv.x; v[1] += bv.y; v[2] += bv.z; v[3] += bv.w;
      __builtin_nontemporal_store(v,
          (f32x4*)&C[(size_t)(brow + wr + mi * 16 + rr * 4 + rsel) * N_DIM + bcol + wc + col4 * 4]);
    }
    WAITL(0);
  }
}

extern "C" void kernel_launch(void* const* d_in, const int* in_sizes, int n_in,
                              void* d_out, int out_size, void* d_ws, size_t ws_size,
                              hipStream_t stream) {
  const float* x    = (const float*)d_in[0];
  const float* a    = (const float*)d_in[1];
  const float* b    = (const float*)d_in[2];
  const float* s    = (const float*)d_in[3];
  const float* bias = (const float*)d_in[4];
  float* out = (float*)d_out;

  unsigned short* xb = (unsigned short*)d_ws;                                        // 32 MB
  unsigned short* wT = (unsigned short*)((char*)d_ws + (size_t)M_DIM * K_DIM * 2);   // 8 MB

  prep_kernel<<<WT_BLOCKS + CVT_BLOCKS, 256, 0, stream>>>(x, a, b, s, xb, wT);
  gemm8_kernel<<<(M_DIM / 256) * (N_DIM / 256), 512, 0, stream>>>(xb, wT, bias, out);
}